// Round 14
// baseline (206.981 us; speedup 1.0000x reference)
//
#include <hip/hip_runtime.h>

#define H1 64
#define GAMMA 0.1f

// ---- fused-DPP wave reduction (single v_add_f32_dpp per stage, no movs) ----
// Classic GCN sequence: row_shr 1/2/4/8 then row_bcast15 (rows 1,3 only),
// row_bcast31 (rows 2,3 only) -> lane 63 holds the 64-lane sum.
// update_dpp(old=0,...): lanes disabled by row_mask add 0 (old), so sums stay
// correct. bound_ctrl=true: out-of-row sources read 0.
template <int CTRL, int ROWMASK>
static __device__ __forceinline__ float dpp_madd(float v) {
    int p = __builtin_amdgcn_update_dpp(0, __float_as_int(v), CTRL, ROWMASK,
                                        0xF, true);
    return v + __int_as_float(p);
}

// full 64-lane sum -> uniform float (via readlane 63 -> SGPR).
static __device__ __forceinline__ float wave_sum(float v) {
    v = dpp_madd<0x111, 0xF>(v);   // row_shr:1
    v = dpp_madd<0x112, 0xF>(v);   // row_shr:2
    v = dpp_madd<0x114, 0xF>(v);   // row_shr:4
    v = dpp_madd<0x118, 0xF>(v);   // row_shr:8  -> lane15 of each row = row sum
    v = dpp_madd<0x142, 0xA>(v);   // row_bcast15 -> rows 1,3 accumulate
    v = dpp_madd<0x143, 0xC>(v);   // row_bcast31 -> rows 2,3 accumulate
    return __int_as_float(__builtin_amdgcn_readlane(__float_as_int(v), 63));
}

// One wave per row m; lane h owns channel h's scalar SIR ODE (beta constant).
// R never integrated: S+I+R conserved per channel ->
//   dot(R,W3_k) = cst_k - dot(S,W3_k) - dot(I,W3_k).
// All 8 dots reduced to wave-uniform scalars via fused-DPP chains + readlane;
// the 64->4->1 head + softmax then run redundantly on uniform values in every
// lane (no cross-lane traffic at all). bs2 cancels in softmax.
// NO lambdas / arrays: named scalars only (round-3: alloca went to LDS/scratch).
__global__ __launch_bounds__(256) void sir_ode_kernel(
    const float* __restrict__ x,
    const float* __restrict__ t,
    const float* __restrict__ W_s1,
    const float* __restrict__ b_s1,
    const float* __restrict__ W3,
    const float* __restrict__ b3,
    const float* __restrict__ Ws2,
    float* __restrict__ out,
    int M, int T)
{
    const int gtid = blockIdx.x * blockDim.x + threadIdx.x;
    const int m = gtid >> 6;
    const int lane = threadIdx.x & 63;
    if (m >= M) return;          // never taken (grid exact) -> full exec mask

    const int C = H1 + 3;

    const float w30 = W3[0 * H1 + lane];
    const float w31 = W3[1 * H1 + lane];
    const float w32 = W3[2 * H1 + lane];
    const float w33 = W3[3 * H1 + lane];

    // uniform head constants
    const float b30 = b3[0], b31 = b3[1], b32 = b3[2], b33 = b3[3];
    const float u20 = Ws2[0], u21 = Ws2[1], u22 = Ws2[2], u23 = Ws2[3];

    const float S0  = x[(size_t)m * C + 0];
    const float I0  = x[(size_t)m * C + 1];
    const float bgv = x[(size_t)m * C + 3 + lane];
    const float w1  = W_s1[lane];
    const float bb  = b_s1[lane];

    float S = fmaxf(fmaf(S0, w1, bb), 0.0f);
    float I = fmaxf(fmaf(I0, w1, bb), 0.0f);
    const float beta = 0.5f / (1.0f + __expf(-bgv));

    // conserved totals: cb_k = b3_k + sum_h W3[k,h]*(S0c+I0c)[h]
    const float tot = S + I;
    const float cb0 = b30 + wave_sum(tot * w30);
    const float cb1 = b31 + wave_sum(tot * w31);
    const float cb2 = b32 + wave_sum(tot * w32);
    const float cb3 = b33 + wave_sum(tot * w33);

    const size_t TM = (size_t)T * (size_t)M;
    float* op = out + (size_t)m;          // advances by M each step
    float t_cur = t[0];

    for (int ti = 0; ti < T; ++ti) {
        const bool last = (ti + 1 >= T);
        const float t_next = last ? t_cur : t[ti + 1];
        const float dt = t_next - t_cur;          // 0 on the last step
        t_cur = t_next;

        // ---- 8 wave-uniform dots (4 S, 4 I); 6 fused dpp-adds + readlane each
        const float sS0 = wave_sum(S * w30);
        const float sS1 = wave_sum(S * w31);
        const float sS2 = wave_sum(S * w32);
        const float sS3 = wave_sum(S * w33);
        const float sI0 = wave_sum(I * w30);
        const float sI1 = wave_sum(I * w31);
        const float sI2 = wave_sum(I * w32);
        const float sI3 = wave_sum(I * w33);

        // ---- head on uniform values, redundantly in all lanes
        float l0 = 0.0f, l1 = 0.0f, l2 = 0.0f;
        {
            float hS = fmaxf(sS0 + b30, 0.0f);
            float hI = fmaxf(sI0 + b30, 0.0f);
            float hR = fmaxf(cb0 - sS0 - sI0, 0.0f);
            l0 = fmaf(hS, u20, l0); l1 = fmaf(hI, u20, l1); l2 = fmaf(hR, u20, l2);
        }
        {
            float hS = fmaxf(sS1 + b31, 0.0f);
            float hI = fmaxf(sI1 + b31, 0.0f);
            float hR = fmaxf(cb1 - sS1 - sI1, 0.0f);
            l0 = fmaf(hS, u21, l0); l1 = fmaf(hI, u21, l1); l2 = fmaf(hR, u21, l2);
        }
        {
            float hS = fmaxf(sS2 + b32, 0.0f);
            float hI = fmaxf(sI2 + b32, 0.0f);
            float hR = fmaxf(cb2 - sS2 - sI2, 0.0f);
            l0 = fmaf(hS, u22, l0); l1 = fmaf(hI, u22, l1); l2 = fmaf(hR, u22, l2);
        }
        {
            float hS = fmaxf(sS3 + b33, 0.0f);
            float hI = fmaxf(sI3 + b33, 0.0f);
            float hR = fmaxf(cb3 - sS3 - sI3, 0.0f);
            l0 = fmaf(hS, u23, l0); l1 = fmaf(hI, u23, l1); l2 = fmaf(hR, u23, l2);
        }

        // softmax over the 3 states (bs2 cancels)
        float mx = fmaxf(fmaxf(l0, l1), l2);
        float e0 = __expf(l0 - mx);
        float e1 = __expf(l1 - mx);
        float e2 = __expf(l2 - mx);
        float rs = 1.0f / (e0 + e1 + e2);

        if (lane < 3) {
            float v = (lane == 0) ? e0 * rs : ((lane == 1) ? e1 * rs : e2 * rs);
            op[(size_t)lane * TM] = v;
        }
        op += M;

        // ---- RK4 advance of (S,I); dt==0 on the last step is an exact no-op
        const float hdt = 0.5f * dt;
        float inf1 = beta * S * I;
        float I2 = fmaf(hdt, fmaf(-GAMMA, I, inf1), I);
        float S2 = fmaf(-hdt, inf1, S);
        float inf2 = beta * S2 * I2;
        float S3 = fmaf(-hdt, inf2, S);
        float I3 = fmaf(hdt, fmaf(-GAMMA, I2, inf2), I);
        float inf3 = beta * S3 * I3;
        float S4 = fmaf(-dt, inf3, S);
        float I4 = fmaf(dt, fmaf(-GAMMA, I3, inf3), I);
        float inf4 = beta * S4 * I4;
        float sumInf = fmaf(2.0f, inf2 + inf3, inf1) + inf4;
        float A      = fmaf(2.0f, I2 + I3, I) + I4;
        float w = dt * (1.0f / 6.0f);
        S = fmaf(-w, sumInf, S);
        I = fmaf(w, fmaf(-GAMMA, A, sumInf), I);
    }
}

extern "C" void kernel_launch(void* const* d_in, const int* in_sizes, int n_in,
                              void* d_out, int out_size, void* d_ws, size_t ws_size,
                              hipStream_t stream) {
    const float* x    = (const float*)d_in[0];
    const float* t    = (const float*)d_in[1];
    const float* W_s1 = (const float*)d_in[2];
    const float* b_s1 = (const float*)d_in[3];
    const float* W3   = (const float*)d_in[4];
    const float* b3   = (const float*)d_in[5];
    const float* Ws2  = (const float*)d_in[6];
    // d_in[7] = bs2: cancels in the softmax, unused.
    float* out = (float*)d_out;

    const int M = in_sizes[0] / (H1 + 3);   // 4000
    const int T = in_sizes[1];              // 100

    const int threads = 256;                 // 4 waves/block
    const int blocks = (M * 64 + threads - 1) / threads;
    sir_ode_kernel<<<blocks, threads, 0, stream>>>(x, t, W_s1, b_s1, W3, b3, Ws2,
                                                   out, M, T);
}

// Round 18
// 129.317 us; speedup vs baseline: 1.6006x; 1.6006x over previous
//
#include <hip/hip_runtime.h>

#define H1 64
#define GAMMA 0.1f

// ---- verified cross-lane primitive (r3/r15/r16): full-rowmask DPP xor folds.
// All four stay within a 16-lane row; compiler fuses each into one v_add_f32_dpp.
template <int CTRL>
static __device__ __forceinline__ float dpp_addf(float v) {
    int p = __builtin_amdgcn_update_dpp(0, __float_as_int(v), CTRL, 0xF, 0xF, true);
    return v + __int_as_float(p);
}
// sum over each 16-lane row: after 4 stages every lane holds its row's total
static __device__ __forceinline__ float red16(float v) {
    v = dpp_addf<0xB1>(v);    // quad_perm [1,0,3,2] : xor 1
    v = dpp_addf<0x4E>(v);    // quad_perm [2,3,0,1] : xor 2
    v = dpp_addf<0x141>(v);   // row_half_mirror     : xor 7
    v = dpp_addf<0x140>(v);   // row_mirror          : xor 15
    return v;
}

// FOUR rows per wave: 16-lane group g (= lane>>4) owns row 4w+g; each lane
// owns channels c, c+16, c+32, c+48 of its row. The 8 dot-reductions are
// 16-wide (4 fused DPP adds) and serve all 4 rows in the same instructions.
// R never integrated (S+I+R conserved per channel -> cb_k constants).
// Named scalars only (r3: lambdas/arrays -> LDS/scratch).
__global__ __launch_bounds__(256, 1) void sir_ode_kernel(
    const float* __restrict__ x,
    const float* __restrict__ t,
    const float* __restrict__ W_s1,
    const float* __restrict__ b_s1,
    const float* __restrict__ W3,
    const float* __restrict__ b3,
    const float* __restrict__ Ws2,
    float* __restrict__ out,
    int M, int T)
{
    const int wave = (blockIdx.x * blockDim.x + threadIdx.x) >> 6;
    const int lane = threadIdx.x & 63;
    const int g    = lane >> 4;          // group -> row offset within the 4-pack
    const int c    = lane & 15;          // channel base; owns c,c+16,c+32,c+48
    const int r    = wave * 4 + g;       // this group's row
    if (r >= M) return;                  // never taken (M%4==0, grid exact)

    const int C = H1 + 3;

    // per-lane W3 weights for its four channels
    const float w30a = W3[0*H1 + c], w30b = W3[0*H1 + c+16], w30c = W3[0*H1 + c+32], w30d = W3[0*H1 + c+48];
    const float w31a = W3[1*H1 + c], w31b = W3[1*H1 + c+16], w31c = W3[1*H1 + c+32], w31d = W3[1*H1 + c+48];
    const float w32a = W3[2*H1 + c], w32b = W3[2*H1 + c+16], w32c = W3[2*H1 + c+32], w32d = W3[2*H1 + c+48];
    const float w33a = W3[3*H1 + c], w33b = W3[3*H1 + c+16], w33c = W3[3*H1 + c+32], w33d = W3[3*H1 + c+48];

    // uniform head constants (SGPR-resident)
    const float b30 = b3[0], b31 = b3[1], b32 = b3[2], b33 = b3[3];
    const float u20 = Ws2[0], u21 = Ws2[1], u22 = Ws2[2], u23 = Ws2[3];

    const float S0 = x[(size_t)r * C + 0];
    const float I0 = x[(size_t)r * C + 1];
    const float bga = x[(size_t)r * C + 3 + c];
    const float bgb = x[(size_t)r * C + 3 + c + 16];
    const float bgc = x[(size_t)r * C + 3 + c + 32];
    const float bgd = x[(size_t)r * C + 3 + c + 48];
    const float w1a = W_s1[c],    w1b = W_s1[c+16], w1c = W_s1[c+32], w1d = W_s1[c+48];
    const float b1a = b_s1[c],    b1b = b_s1[c+16], b1c = b_s1[c+32], b1d = b_s1[c+48];

    float Sa = fmaxf(fmaf(S0, w1a, b1a), 0.0f);
    float Ia = fmaxf(fmaf(I0, w1a, b1a), 0.0f);
    float Sb = fmaxf(fmaf(S0, w1b, b1b), 0.0f);
    float Ib = fmaxf(fmaf(I0, w1b, b1b), 0.0f);
    float Sc = fmaxf(fmaf(S0, w1c, b1c), 0.0f);
    float Ic = fmaxf(fmaf(I0, w1c, b1c), 0.0f);
    float Sd = fmaxf(fmaf(S0, w1d, b1d), 0.0f);
    float Id = fmaxf(fmaf(I0, w1d, b1d), 0.0f);
    const float beta_a = 0.5f / (1.0f + __expf(-bga));
    const float beta_b = 0.5f / (1.0f + __expf(-bgb));
    const float beta_c = 0.5f / (1.0f + __expf(-bgc));
    const float beta_d = 0.5f / (1.0f + __expf(-bgd));

    // conserved totals per row: cb_k = b3_k + dot(S0c+I0c, W3_k)
    const float ta = Sa + Ia, tb = Sb + Ib, tc = Sc + Ic, td = Sd + Id;
    const float cb0 = b30 + red16(fmaf(td, w30d, fmaf(tc, w30c, fmaf(tb, w30b, ta * w30a))));
    const float cb1 = b31 + red16(fmaf(td, w31d, fmaf(tc, w31c, fmaf(tb, w31b, ta * w31a))));
    const float cb2 = b32 + red16(fmaf(td, w32d, fmaf(tc, w32c, fmaf(tb, w32b, ta * w32a))));
    const float cb3 = b33 + red16(fmaf(td, w33d, fmaf(tc, w33c, fmaf(tb, w33b, ta * w33a))));

    const size_t TM = (size_t)T * (size_t)M;
    // lanes with c<3 store output component c for row r
    float* op = out + (size_t)c * TM + (size_t)r;   // advances by M each step
    float t_cur = t[0];

    for (int ti = 0; ti < T; ++ti) {
        const bool last = (ti + 1 >= T);
        const float t_next = last ? t_cur : t[ti + 1];
        const float dt = t_next - t_cur;            // 0 on the last step
        t_cur = t_next;

        // ---- 8 per-row dots: 4-channel partial (mul+3fma) then shared red16
        const float sS0 = red16(fmaf(Sd, w30d, fmaf(Sc, w30c, fmaf(Sb, w30b, Sa * w30a))));
        const float sS1 = red16(fmaf(Sd, w31d, fmaf(Sc, w31c, fmaf(Sb, w31b, Sa * w31a))));
        const float sS2 = red16(fmaf(Sd, w32d, fmaf(Sc, w32c, fmaf(Sb, w32b, Sa * w32a))));
        const float sS3 = red16(fmaf(Sd, w33d, fmaf(Sc, w33c, fmaf(Sb, w33b, Sa * w33a))));
        const float sI0 = red16(fmaf(Id, w30d, fmaf(Ic, w30c, fmaf(Ib, w30b, Ia * w30a))));
        const float sI1 = red16(fmaf(Id, w31d, fmaf(Ic, w31c, fmaf(Ib, w31b, Ia * w31a))));
        const float sI2 = red16(fmaf(Id, w32d, fmaf(Ic, w32c, fmaf(Ib, w32b, Ia * w32a))));
        const float sI3 = red16(fmaf(Id, w33d, fmaf(Ic, w33c, fmaf(Ib, w33b, Ia * w33a))));

        // ---- head (per-lane; values uniform within each 16-lane group)
        float l0, l1, l2;
        {
            float hS = fmaxf(sS0 + b30, 0.0f);
            float hI = fmaxf(sI0 + b30, 0.0f);
            float hR = fmaxf(cb0 - sS0 - sI0, 0.0f);
            l0 = hS * u20; l1 = hI * u20; l2 = hR * u20;
        }
        {
            float hS = fmaxf(sS1 + b31, 0.0f);
            float hI = fmaxf(sI1 + b31, 0.0f);
            float hR = fmaxf(cb1 - sS1 - sI1, 0.0f);
            l0 = fmaf(hS, u21, l0); l1 = fmaf(hI, u21, l1); l2 = fmaf(hR, u21, l2);
        }
        {
            float hS = fmaxf(sS2 + b32, 0.0f);
            float hI = fmaxf(sI2 + b32, 0.0f);
            float hR = fmaxf(cb2 - sS2 - sI2, 0.0f);
            l0 = fmaf(hS, u22, l0); l1 = fmaf(hI, u22, l1); l2 = fmaf(hR, u22, l2);
        }
        {
            float hS = fmaxf(sS3 + b33, 0.0f);
            float hI = fmaxf(sI3 + b33, 0.0f);
            float hR = fmaxf(cb3 - sS3 - sI3, 0.0f);
            l0 = fmaf(hS, u23, l0); l1 = fmaf(hI, u23, l1); l2 = fmaf(hR, u23, l2);
        }

        // softmax over the 3 states (bs2 cancels)
        float mx = fmaxf(fmaxf(l0, l1), l2);
        float e0 = __expf(l0 - mx);
        float e1 = __expf(l1 - mx);
        float e2 = __expf(l2 - mx);
        float rs = 1.0f / (e0 + e1 + e2);

        if (c < 3) {
            float v = (c == 0) ? e0 * rs : ((c == 1) ? e1 * rs : e2 * rs);
            *op = v;
        }
        op += M;

        // ---- RK4 for all four channel-systems (independent chains -> ILP)
        const float hdt = 0.5f * dt;
        const float w = dt * (1.0f / 6.0f);
        // system a
        float inf1a = beta_a * Sa * Ia;
        float I2a = fmaf(hdt, fmaf(-GAMMA, Ia, inf1a), Ia);
        float S2a = fmaf(-hdt, inf1a, Sa);
        float inf2a = beta_a * S2a * I2a;
        float S3a = fmaf(-hdt, inf2a, Sa);
        float I3a = fmaf(hdt, fmaf(-GAMMA, I2a, inf2a), Ia);
        float inf3a = beta_a * S3a * I3a;
        float S4a = fmaf(-dt, inf3a, Sa);
        float I4a = fmaf(dt, fmaf(-GAMMA, I3a, inf3a), Ia);
        float inf4a = beta_a * S4a * I4a;
        float sumInfa = fmaf(2.0f, inf2a + inf3a, inf1a) + inf4a;
        float Aa      = fmaf(2.0f, I2a + I3a, Ia) + I4a;
        // system b
        float inf1b = beta_b * Sb * Ib;
        float I2b = fmaf(hdt, fmaf(-GAMMA, Ib, inf1b), Ib);
        float S2b = fmaf(-hdt, inf1b, Sb);
        float inf2b = beta_b * S2b * I2b;
        float S3b = fmaf(-hdt, inf2b, Sb);
        float I3b = fmaf(hdt, fmaf(-GAMMA, I2b, inf2b), Ib);
        float inf3b = beta_b * S3b * I3b;
        float S4b = fmaf(-dt, inf3b, Sb);
        float I4b = fmaf(dt, fmaf(-GAMMA, I3b, inf3b), Ib);
        float inf4b = beta_b * S4b * I4b;
        float sumInfb = fmaf(2.0f, inf2b + inf3b, inf1b) + inf4b;
        float Ab      = fmaf(2.0f, I2b + I3b, Ib) + I4b;
        // system c
        float inf1c = beta_c * Sc * Ic;
        float I2c = fmaf(hdt, fmaf(-GAMMA, Ic, inf1c), Ic);
        float S2c = fmaf(-hdt, inf1c, Sc);
        float inf2c = beta_c * S2c * I2c;
        float S3c = fmaf(-hdt, inf2c, Sc);
        float I3c = fmaf(hdt, fmaf(-GAMMA, I2c, inf2c), Ic);
        float inf3c = beta_c * S3c * I3c;
        float S4c = fmaf(-dt, inf3c, Sc);
        float I4c = fmaf(dt, fmaf(-GAMMA, I3c, inf3c), Ic);
        float inf4c = beta_c * S4c * I4c;
        float sumInfc = fmaf(2.0f, inf2c + inf3c, inf1c) + inf4c;
        float Ac      = fmaf(2.0f, I2c + I3c, Ic) + I4c;
        // system d
        float inf1d = beta_d * Sd * Id;
        float I2d = fmaf(hdt, fmaf(-GAMMA, Id, inf1d), Id);
        float S2d = fmaf(-hdt, inf1d, Sd);
        float inf2d = beta_d * S2d * I2d;
        float S3d = fmaf(-hdt, inf2d, Sd);
        float I3d = fmaf(hdt, fmaf(-GAMMA, I2d, inf2d), Id);
        float inf3d = beta_d * S3d * I3d;
        float S4d = fmaf(-dt, inf3d, Sd);
        float I4d = fmaf(dt, fmaf(-GAMMA, I3d, inf3d), Id);
        float inf4d = beta_d * S4d * I4d;
        float sumInfd = fmaf(2.0f, inf2d + inf3d, inf1d) + inf4d;
        float Ad      = fmaf(2.0f, I2d + I3d, Id) + I4d;

        Sa = fmaf(-w, sumInfa, Sa);
        Ia = fmaf(w, fmaf(-GAMMA, Aa, sumInfa), Ia);
        Sb = fmaf(-w, sumInfb, Sb);
        Ib = fmaf(w, fmaf(-GAMMA, Ab, sumInfb), Ib);
        Sc = fmaf(-w, sumInfc, Sc);
        Ic = fmaf(w, fmaf(-GAMMA, Ac, sumInfc), Ic);
        Sd = fmaf(-w, sumInfd, Sd);
        Id = fmaf(w, fmaf(-GAMMA, Ad, sumInfd), Id);
    }
}

extern "C" void kernel_launch(void* const* d_in, const int* in_sizes, int n_in,
                              void* d_out, int out_size, void* d_ws, size_t ws_size,
                              hipStream_t stream) {
    const float* x    = (const float*)d_in[0];
    const float* t    = (const float*)d_in[1];
    const float* W_s1 = (const float*)d_in[2];
    const float* b_s1 = (const float*)d_in[3];
    const float* W3   = (const float*)d_in[4];
    const float* b3   = (const float*)d_in[5];
    const float* Ws2  = (const float*)d_in[6];
    // d_in[7] = bs2: cancels in the softmax, unused.
    float* out = (float*)d_out;

    const int M = in_sizes[0] / (H1 + 3);   // 4000
    const int T = in_sizes[1];              // 100

    // 4 rows per wave -> M/4 waves; 4 waves per 256-thread block
    const int waves  = (M + 3) / 4;
    const int threads = 256;
    const int blocks = (waves * 64 + threads - 1) / threads;
    sir_ode_kernel<<<blocks, threads, 0, stream>>>(x, t, W_s1, b_s1, W3, b3, Ws2,
                                                   out, M, T);
}